// Round 7
// baseline (290.179 us; speedup 1.0000x reference)
//
#include <hip/hip_runtime.h>

// Problem constants
#define BATCH 8
#define CIN   128
#define HH    112
#define WW    112
#define COUT  256
#define KOFF  18          // 2*K*K offset channels
#define HW    (HH*WW)     // 12544
#define NPIX  (BATCH*HW)  // 100352
#define BK    64          // K-step (bf16 elems)

typedef __attribute__((ext_vector_type(8))) short short8;
typedef __attribute__((ext_vector_type(4))) float f32x4;

__device__ __forceinline__ unsigned short f2bf(float f) {
    union { float f; unsigned u; } v; v.f = f;
    unsigned r = v.u + 0x7fffu + ((v.u >> 16) & 1u);   // round-to-nearest-even
    return (unsigned short)(r >> 16);
}
__device__ __forceinline__ float bflo(unsigned u) {
    union { unsigned u; float f; } v; v.u = u << 16; return v.f;
}
__device__ __forceinline__ float bfhi(unsigned u) {
    union { unsigned u; float f; } v; v.u = u & 0xffff0000u; return v.f;
}

// async global -> LDS, 16B per lane. LDS dest is wave-uniform base; HW writes
// base + lane*16. Global src is per-lane (zero-page / swizzle redirect ok).
__device__ __forceinline__ void gload16(const unsigned short* g, unsigned short* l) {
    __builtin_amdgcn_global_load_lds(
        (const __attribute__((address_space(1))) void*)g,
        (__attribute__((address_space(3))) void*)l, 16, 0, 0);
}

// raw workgroup barrier WITHOUT the vmcnt(0) drain __syncthreads carries;
// sched_barrier(0) pins VMEM/ds/MFMA ordering around it (rule #18).
#define RAW_BARRIER() do { \
    __builtin_amdgcn_sched_barrier(0); \
    __builtin_amdgcn_s_barrier(); \
    __builtin_amdgcn_sched_barrier(0); \
} while (0)

// ---------------------------------------------------------------------------
// Kernel 0: fused prep — main-weight convert (blocks 0..1151), offset-weight
// convert N-padded 18->32 (blocks 1152..1295), zero page (block 1296).
// ---------------------------------------------------------------------------
__global__ __launch_bounds__(256) void prep_kernel(
    const float* __restrict__ cw, const float* __restrict__ ow,
    unsigned short* __restrict__ wt, unsigned short* __restrict__ owt,
    unsigned short* __restrict__ zbuf)
{
    const int bid = blockIdx.x;
    const int tid = threadIdx.x;
    if (bid < 1152) {
        const int i  = bid * 256 + tid;            // 294912 exact
        const int co = i / 1152;
        const int k  = i % 1152;
        const int t  = k >> 7;
        const int ci = k & 127;
        wt[i] = f2bf(cw[((size_t)(co * CIN + ci)) * 9 + t]);
    } else if (bid < 1296) {
        const int i  = (bid - 1152) * 256 + tid;   // 36864 exact
        const int co = i / 1152;
        const int k  = i % 1152;
        const int t  = k >> 7;
        const int ci = k & 127;
        owt[i] = (co < KOFF) ? f2bf(ow[((size_t)(co * CIN + ci)) * 9 + t]) : 0;
    } else {
        zbuf[tid] = 0;
    }
}

// ---------------------------------------------------------------------------
// Kernel 1: x NCHW fp32 -> NHWC bf16 (xh[p][128]) via LDS transpose.
// ---------------------------------------------------------------------------
__global__ __launch_bounds__(256) void nhwc_kernel(
    const float* __restrict__ x, unsigned short* __restrict__ xh)
{
    __shared__ unsigned int sm[64 * 65];
    const int tid = threadIdx.x;
    const int px  = tid & 63;
    const int cig = tid >> 6;
    const int p0  = blockIdx.x * 64;          // 1568 blocks; never straddles b
    const int b   = p0 / HW;
    const int rem0 = p0 % HW;
    const float* xb = x + (size_t)b * CIN * HW + rem0 + px;

    const int c0 = 2 * cig;
#pragma unroll
    for (int k = 0; k < 16; ++k) {
        const int ci = c0 + 8 * k;
        const float a0 = xb[(size_t)ci * HW];
        const float a1 = xb[(size_t)(ci + 1) * HW];
        sm[px * 65 + (ci >> 1)] = (unsigned)f2bf(a0) | ((unsigned)f2bf(a1) << 16);
    }
    __syncthreads();

    const int row = tid >> 2, chunk = tid & 3;
    unsigned int u[16];
#pragma unroll
    for (int c = 0; c < 16; ++c) u[c] = sm[row * 65 + chunk * 16 + c];
    uint4* gv = (uint4*)(xh + ((size_t)(p0 + row)) * 128 + chunk * 32);
#pragma unroll
    for (int j = 0; j < 4; ++j) {
        uint4 t; t.x = u[4*j]; t.y = u[4*j+1]; t.z = u[4*j+2]; t.w = u[4*j+3];
        gv[j] = t;
    }
}

// ---------------------------------------------------------------------------
// Kernel 2: FUSED offset conv + deformable sampling.
// Phase 1 (r4-verified): implicit-GEMM MFMA, M=128 px, N=32 (18 used),
// K=1152, counted-vmcnt double-buffer, XOR-swizzled LDS; offsets land in
// sm_off (fp32) — po never goes to global.
// Phase 2 (r4-verified sampler): this block's 128 pixels sampled with fp32
// offsets straight from LDS (+bias). Image-per-XCD swizzle kept: all xh
// gathers stay in this XCD's L2.
// ---------------------------------------------------------------------------
__global__ __launch_bounds__(256) void offset_sample_kernel(
    const unsigned short* __restrict__ xh, const unsigned short* __restrict__ owt,
    const float* __restrict__ ob, const unsigned short* __restrict__ zbuf,
    unsigned short* __restrict__ sampled)
{
    __shared__ __align__(16) unsigned short As[2][128 * BK];  // 32 KB
    __shared__ __align__(16) unsigned short Bs[2][32 * BK];   // 8 KB
    __shared__ float sm_off[128][20];                         // 10.2 KB
    __shared__ float sb_bias[KOFF];

    const int tid  = threadIdx.x;
    const int lane = tid & 63;
    const int wave = tid >> 6;
    const int bid  = blockIdx.x;               // 784 = 8*98 exact
    const int swz  = (bid & 7) * 98 + (bid >> 3);   // bijective XCD swizzle
    const int b    = swz / 98;                 // XCD x -> image x
    const int p0   = (swz % 98) * 128;

    if (tid < KOFF) sb_bias[tid] = ob[tid];

    const int rlane = lane >> 3;         // 0..7 : row within 8-row DMA group
    const int chunk = lane & 7;          // physical 16B chunk this lane writes
    const int csw   = chunk ^ rlane;     // pre-swizzled source chunk

    const unsigned short* xb = xh + (size_t)b * HW * 128;

    int aoff0[4], py4[4], px4[4];
#pragma unroll
    for (int j = 0; j < 4; ++j) {
        const int row = wave * 32 + j * 8 + rlane;
        const int pp  = p0 + row;
        py4[j] = pp / WW; px4[j] = pp % WW;
        aoff0[j] = pp * 128 + csw * 8;
    }
    const int boff = (wave * 8 + rlane) * 1152 + csw * 8;
    const int zoff = (int)(zbuf - xb) + csw * 8;

    const int col  = lane & 15;
    const int quad = lane >> 4;
    const int m0   = wave * 32;
    const int sw   = col & 7;                 // = frag row & 7
    const int cb0  = (quad ^ sw) << 4;        // byte offset of 16B chunk, kk=0
    const int cb1  = ((quad + 4) ^ sw) << 4;  // kk=32

    f32x4 acc[2][2];
#pragma unroll
    for (int i = 0; i < 2; ++i)
#pragma unroll
        for (int j = 0; j < 2; ++j) acc[i][j] = (f32x4)0.f;

    int ao[4];

#define MK_AOFF(T) do { \
    const int dy_ = (T) / 3 - 1, dx_ = (T) % 3 - 1; \
    _Pragma("unroll") for (int j = 0; j < 4; ++j) { \
        const bool v_ = ((unsigned)(py4[j] + dy_) < HH) && ((unsigned)(px4[j] + dx_) < WW); \
        ao[j] = v_ ? (aoff0[j] + (dy_ * WW + dx_) * 128) : zoff; \
    } \
} while (0)

#define STAGE(BUF, T, CI0) do { \
    _Pragma("unroll") for (int j = 0; j < 4; ++j) \
        gload16(xb + ao[j] + (CI0), &As[BUF][(wave * 32 + j * 8) * BK]); \
    gload16(owt + boff + (T) * 128 + (CI0), &Bs[BUF][(wave * 8) * BK]); \
} while (0)

#define COMPUTE(BUF) do { \
    const char* Ab_ = (const char*)As[BUF]; \
    const char* Bb_ = (const char*)Bs[BUF]; \
    short8 af_[2], bf_[2]; \
    _Pragma("unroll") for (int f = 0; f < 2; ++f) \
        af_[f] = *(const short8*)(Ab_ + (m0 + f * 16 + col) * 128 + cb0); \
    _Pragma("unroll") for (int f = 0; f < 2; ++f) \
        bf_[f] = *(const short8*)(Bb_ + (f * 16 + col) * 128 + cb0); \
    _Pragma("unroll") for (int fm = 0; fm < 2; ++fm) \
    _Pragma("unroll") for (int fn = 0; fn < 2; ++fn) \
        acc[fm][fn] = __builtin_amdgcn_mfma_f32_16x16x32_bf16(af_[fm], bf_[fn], acc[fm][fn], 0, 0, 0); \
    _Pragma("unroll") for (int f = 0; f < 2; ++f) \
        af_[f] = *(const short8*)(Ab_ + (m0 + f * 16 + col) * 128 + cb1); \
    _Pragma("unroll") for (int f = 0; f < 2; ++f) \
        bf_[f] = *(const short8*)(Bb_ + (f * 16 + col) * 128 + cb1); \
    _Pragma("unroll") for (int fm = 0; fm < 2; ++fm) \
    _Pragma("unroll") for (int fn = 0; fn < 2; ++fn) \
        acc[fm][fn] = __builtin_amdgcn_mfma_f32_16x16x32_bf16(af_[fm], bf_[fn], acc[fm][fn], 0, 0, 0); \
} while (0)

    MK_AOFF(0);
    STAGE(0, 0, 0);
#pragma unroll
    for (int t = 0; t < 9; ++t) {
        RAW_BARRIER();                               // release buf1
        STAGE(1, t, 64);
        asm volatile("s_waitcnt vmcnt(5)" ::: "memory");   // buf0 loads landed
        RAW_BARRIER();                               // published to all waves
        COMPUTE(0);
        RAW_BARRIER();                               // release buf0
        if (t < 8) {
            MK_AOFF(t + 1);
            STAGE(0, t + 1, 0);
            asm volatile("s_waitcnt vmcnt(5)" ::: "memory");  // buf1 loads landed
        } else {
            asm volatile("s_waitcnt vmcnt(0)" ::: "memory");  // epilogue drain
        }
        RAW_BARRIER();
        COMPUTE(1);
    }
#undef MK_AOFF
#undef STAGE
#undef COMPUTE

    // D (row = m0+fm*16+quad*4+r, col = fn*16+(lane&15)) -> sm_off
#pragma unroll
    for (int fm = 0; fm < 2; ++fm)
#pragma unroll
        for (int fn = 0; fn < 2; ++fn) {
            const int c = fn * 16 + col;
            if (c < KOFF) {
                const int rb = m0 + fm * 16 + quad * 4;
#pragma unroll
                for (int r = 0; r < 4; ++r) sm_off[rb + r][c] = acc[fm][fn][r];
            }
        }
    __syncthreads();

    // ---- Phase 2: sample this block's 128 pixels (fp32 offsets from LDS) ----
    {
        const int cl  = lane & 15;
        const int ppx = lane >> 4;
        const unsigned short* xg = xh + ((size_t)b * HW) * 128 + cl * 8;

#pragma unroll 1
        for (int pass = 0; pass < 8; ++pass) {
            const int px  = pass * 16 + wave * 4 + ppx;   // 0..127
            const int rem = p0 + px;                      // within-image pixel
            const int y   = rem / WW;
            const int xx  = rem % WW;

            int   sidx[9][4];
            float swt[9][4];
#pragma unroll
            for (int s = 0; s < 9; ++s) {
                const int ky = s / 3, kx = s % 3;
                const float oy = sm_off[px][s]     + sb_bias[s];
                const float ox = sm_off[px][9 + s] + sb_bias[9 + s];
                const float sy = (float)(y + ky - 1) + oy;
                const float sx = (float)(xx + kx - 1) + ox;
                const float y0f = floorf(sy), x0f = floorf(sx);
                const int   y0 = (int)y0f, x0 = (int)x0f;
                const float wy1 = sy - y0f, wx1 = sx - x0f;
                const float wy0 = 1.f - wy1, wx0 = 1.f - wx1;
                const int y0c = min(max(y0, 0), HH - 1), y1c = min(max(y0 + 1, 0), HH - 1);
                const int x0c = min(max(x0, 0), WW - 1), x1c = min(max(x0 + 1, 0), WW - 1);
                const bool vy0 = (unsigned)y0 < HH, vy1 = (unsigned)(y0 + 1) < HH;
                const bool vx0 = (unsigned)x0 < WW, vx1 = (unsigned)(x0 + 1) < WW;
                sidx[s][0] = y0c * WW + x0c; swt[s][0] = (vy0 && vx0) ? wy0 * wx0 : 0.f;
                sidx[s][1] = y0c * WW + x1c; swt[s][1] = (vy0 && vx1) ? wy0 * wx1 : 0.f;
                sidx[s][2] = y1c * WW + x0c; swt[s][2] = (vy1 && vx0) ? wy1 * wx0 : 0.f;
                sidx[s][3] = y1c * WW + x1c; swt[s][3] = (vy1 && vx1) ? wy1 * wx1 : 0.f;
            }

            float sa[8];
#pragma unroll
            for (int j = 0; j < 8; ++j) sa[j] = 0.f;

#pragma unroll
            for (int s = 0; s < 9; ++s) {
#pragma unroll
                for (int c = 0; c < 4; ++c) {
                    const uint4 v = *(const uint4*)(xg + (size_t)sidx[s][c] * 128);
                    const float w = swt[s][c];
                    sa[0] += bflo(v.x) * w; sa[1] += bfhi(v.x) * w;
                    sa[2] += bflo(v.y) * w; sa[3] += bfhi(v.y) * w;
                    sa[4] += bflo(v.z) * w; sa[5] += bfhi(v.z) * w;
                    sa[6] += bflo(v.w) * w; sa[7] += bfhi(v.w) * w;
                }
            }

            uint4 o;
            o.x = (unsigned)f2bf(sa[0]) | ((unsigned)f2bf(sa[1]) << 16);
            o.y = (unsigned)f2bf(sa[2]) | ((unsigned)f2bf(sa[3]) << 16);
            o.z = (unsigned)f2bf(sa[4]) | ((unsigned)f2bf(sa[5]) << 16);
            o.w = (unsigned)f2bf(sa[6]) | ((unsigned)f2bf(sa[7]) << 16);
            *(uint4*)(sampled + ((size_t)(b * HW + rem)) * 128 + cl * 8) = o;
        }
    }
}

// ---------------------------------------------------------------------------
// Kernel 3: implicit-GEMM 3x3 conv, 256x256-tile phase-split schedule
// (r6-verified, unchanged).
// ---------------------------------------------------------------------------
__global__ __launch_bounds__(512, 2) void conv_mfma_kernel(
    const unsigned short* __restrict__ sampled, const unsigned short* __restrict__ wt,
    const unsigned short* __restrict__ zbuf, float* __restrict__ out)
{
    __shared__ __align__(16) unsigned short As[2][256 * BK];   // 64 KB
    __shared__ __align__(16) unsigned short Bs[2][256 * BK];   // 64 KB

    const int tid  = threadIdx.x;
    const int lane = tid & 63;
    const int wid  = tid >> 6;                 // 0..7
    const int bid  = blockIdx.x;               // 392 = 8*49 exact
    const int swz  = (bid & 7) * 49 + (bid >> 3);   // bijective XCD swizzle
    const int b    = swz / 49;                 // XCD x -> image x
    const int p0   = (swz % 49) * 256;

    const int rlane = lane >> 3;         // 0..7 : row within 8-row DMA group
    const int chunk = lane & 7;          // physical 16B chunk this lane writes
    const int csw   = chunk ^ rlane;     // pre-swizzled source chunk

    const unsigned short* sb = sampled + (size_t)b * HW * 128;

    int aoff0[4], boff0[4], py4[4], px4[4];
#pragma unroll
    for (int j = 0; j < 4; ++j) {
        const int row = wid * 32 + j * 8 + rlane;   // 0..255 across 8 waves
        const int pp  = p0 + row;
        py4[j] = pp / WW; px4[j] = pp % WW;
        aoff0[j] = pp * 128 + csw * 8;
        boff0[j] = row * 1152 + csw * 8;            // n0 = 0 (full Cout)
    }
    const int zoff = (int)(zbuf - sb) + csw * 8;

    const int col  = lane & 15;
    const int quad = lane >> 4;
    const int wr   = (wid >> 2) * 128;        // M-group: 0 or 128
    const int wc   = (wid & 3) * 64;          // N-group: 0/64/128/192
    const int sw   = col & 7;                 // = frag row & 7
    const int cb0  = (quad ^ sw) << 4;        // byte offset of 16B chunk, kk=0
    const int cb1  = ((quad + 4) ^ sw) << 4;  // kk=32

    f32x4 acc[8][4];
#pragma unroll
    for (int i = 0; i < 8; ++i)
#pragma unroll
        for (int j = 0; j < 4; ++j) acc[i][j] = (f32x4)0.f;

    short8 bf_[8];
    int ao[4], aon[4];

#define MK_AOFF(AO, TAP) do { \
    const int dy_ = (TAP) / 3 - 1, dx_ = (TAP) % 3 - 1; \
    const int d_  = (dy_ * WW + dx_) * 128; \
    _Pragma("unroll") for (int j = 0; j < 4; ++j) { \
        const bool v_ = ((unsigned)(py4[j] + dy_) < HH) && ((unsigned)(px4[j] + dx_) < WW); \
        AO[j] = v_ ? (aoff0[j] + d_) : zoff; \
    } \
} while (0)

#define ISSUE_A2(BUF, AO, J0, CI) do { \
    gload16(sb + AO[J0] + (CI),       &As[BUF][(wid * 32 + (J0) * 8) * BK]); \
    gload16(sb + AO[(J0) + 1] + (CI), &As[BUF][(wid * 32 + ((J0) + 1) * 8) * BK]); \
} while (0)

#define ISSUE_B2(BUF, TAP, J0, CI) do { \
    gload16(wt + boff0[J0] + (TAP) * 128 + (CI),       &Bs[BUF][(wid * 32 + (J0) * 8) * BK]); \
    gload16(wt + boff0[(J0) + 1] + (TAP) * 128 + (CI), &Bs[BUF][(wid * 32 + ((J0) + 1) * 8) * BK]); \
} while (0)

#define PH_B_READ(BUF) do { \
    const char* Bb_ = (const char*)Bs[BUF]; \
    _Pragma("unroll") for (int fn = 0; fn < 4; ++fn) { \
        bf_[fn * 2]     = *(const short8*)(Bb_ + (wc + fn * 16 + col) * 128 + cb0); \
        bf_[fn * 2 + 1] = *(const short8*)(Bb_ + (wc + fn * 16 + col) * 128 + cb1); \
    } \
} while (0)

#define PHASE(BUF, P) do { \
    const char* Ab_ = (const char*)As[BUF]; \
    short8 a0k0 = *(const short8*)(Ab_ + (wr + (2 * (P)) * 16 + col) * 128 + cb0); \
    short8 a0k1 = *(const short8*)(Ab_ + (wr + (2 * (P)) * 16 + col) * 128 + cb1); \
    short8 a1k0 = *(const short8*)(Ab_ + (wr + (2 * (P) + 1) * 16 + col) * 128 + cb0); \
    short8 a1k1 = *(const short8*)(Ab_ + (wr + (2 * (P) + 1) * 16 + col) * 128 + cb1); \
    asm volatile("s_waitcnt lgkmcnt(0)" ::: "memory"); \
    __builtin_amdgcn_sched_barrier(0); \
    __builtin_amdgcn_s_setprio(1); \
    _Pragma("unroll") for (int fn = 0; fn < 4; ++fn) { \
        acc[2 * (P)][fn]     = __builtin_amdgcn_mfma_f32_16x16x32_bf16(a0k0, bf_[fn * 2],     acc[2 * (P)][fn],     0, 0, 0); \
        acc[2 * (P)][fn]     = __builtin_amdgcn_mfma_f32_16x16x32_bf16(a0k1, bf_[fn * 2 + 1], acc[2 * (P)][fn],     0, 0, 0); \
        acc[2 * (P) + 1][fn] = __builtin_amdgcn_mfma_f32_16x16x32_bf16(a1k0, bf_[fn * 2],     acc[2 * (P) + 1][fn], 0, 0, 0); \
        acc[2 * (P) + 1][fn] = __builtin_amdgcn_mfma_f32_16x16x32_bf16(a1k1, bf_[fn * 2 + 1], acc[2 * (P) + 1][fn], 0, 0, 0); \
    } \
    __builtin_amdgcn_s_setprio(0); \
} while (0)

    // prologue: stage K-tile 0 (tap 0, ci=0) into buf0 — 8 gloads/wave
    MK_AOFF(ao, 0);
    ISSUE_A2(0, ao, 0, 0); ISSUE_A2(0, ao, 2, 0);
    ISSUE_B2(0, 0, 0, 0);  ISSUE_B2(0, 0, 2, 0);

#pragma unroll 1
    for (int t = 0; t < 9; ++t) {
        // ---- K-tile 2t : read buf0 (ci=0) ; prefetch 2t+1 -> buf1 ----
        RAW_BARRIER();                                   // buf1 free (all waves)
        ISSUE_A2(1, ao, 0, 64);
        asm volatile("s_waitcnt vmcnt(2)" ::: "memory"); // own buf0 loads landed
        RAW_BARRIER();                                   // buf0 published
        PH_B_READ(0);
        PHASE(0, 0);
        ISSUE_A2(1, ao, 2, 64);
        PHASE(0, 1);
        ISSUE_B2(1, t, 0, 64);
        PHASE(0, 2);
        ISSUE_B2(1, t, 2, 64);
        PHASE(0, 3);
        // ---- K-tile 2t+1 : read buf1 (ci=64) ; prefetch 2t+2 -> buf0 ----
        RAW_BARRIER();                                   // buf0 free
        if (t < 8) {
            MK_AOFF(aon, t + 1);
            ISSUE_A2(0, aon, 0, 0);
            asm volatile("s_waitcnt vmcnt(2)" ::: "memory");
        } else {
            asm volatile("s_waitcnt vmcnt(0)" ::: "memory");  // final drain
        }
        RAW_BARRIER();                                   // buf1 published
        PH_B_READ(1);
        PHASE(1, 0);
        if (t < 8) ISSUE_A2(0, aon, 2, 0);
        PHASE(1, 1);
        if (t < 8) ISSUE_B2(0, t + 1, 0, 0);
        PHASE(1, 2);
        if (t < 8) ISSUE_B2(0, t + 1, 2, 0);
        PHASE(1, 3);
        if (t < 8) {
#pragma unroll
            for (int j = 0; j < 4; ++j) ao[j] = aon[j];
        }
    }
#undef MK_AOFF
#undef ISSUE_A2
#undef ISSUE_B2
#undef PH_B_READ
#undef PHASE

    // C-write: row = p0 + wr + fm*16 + quad*4 + r, col = wc + fn*16 + (lane&15)
#pragma unroll
    for (int fm = 0; fm < 8; ++fm) {
        const int pix = p0 + wr + fm * 16 + quad * 4;
#pragma unroll
        for (int fn = 0; fn < 4; ++fn) {
            const int co = wc + fn * 16 + col;
            float* op = out + ((size_t)(b * COUT + co)) * HW + pix;
            *(f32x4*)op = acc[fm][fn];
        }
    }
}

// ---------------------------------------------------------------------------
extern "C" void kernel_launch(void* const* d_in, const int* in_sizes, int n_in,
                              void* d_out, int out_size, void* d_ws, size_t ws_size,
                              hipStream_t stream)
{
    const float* x  = (const float*)d_in[0];   // (8,128,112,112)
    const float* ow = (const float*)d_in[1];   // (18,128,3,3)
    const float* ob = (const float*)d_in[2];   // (18,)
    const float* cw = (const float*)d_in[3];   // (256,128,3,3)
    float* out = (float*)d_out;                // (8,256,112,112)

    // ws layout kept from r4/r6 (po region now unused):
    // po 3.6MB | sampled 25.7MB | wt 0.59MB | xh 25.7MB | owt 74KB | zbuf 512B
    unsigned int*   po      = (unsigned int*)d_ws;
    unsigned short* sampled = (unsigned short*)(po + (size_t)NPIX * 9);
    unsigned short* wtb     = sampled + (size_t)NPIX * 128;
    unsigned short* xh      = wtb + (size_t)COUT * 1152;
    unsigned short* owt     = xh + (size_t)NPIX * 128;
    unsigned short* zbuf    = owt + (size_t)32 * 1152;

    prep_kernel<<<dim3(1297), dim3(256), 0, stream>>>(cw, ow, wtb, owt, zbuf);
    nhwc_kernel<<<dim3(NPIX / 64), dim3(256), 0, stream>>>(x, xh);
    offset_sample_kernel<<<dim3(784), dim3(256), 0, stream>>>(xh, owt, ob, zbuf, sampled);
    conv_mfma_kernel<<<dim3(392), dim3(512), 0, stream>>>(sampled, wtb, zbuf, out);
}

// Round 8
// 275.347 us; speedup vs baseline: 1.0539x; 1.0539x over previous
//
#include <hip/hip_runtime.h>

// Problem constants
#define BATCH 8
#define CIN   128
#define HH    112
#define WW    112
#define COUT  256
#define KOFF  18          // 2*K*K offset channels
#define HW    (HH*WW)     // 12544
#define NPIX  (BATCH*HW)  // 100352
#define BK    64          // K-step (bf16 elems)
#define BM3   224         // conv M-tile (divides 12544 -> 56 tiles/image, grid 448)

typedef __attribute__((ext_vector_type(8))) short short8;
typedef __attribute__((ext_vector_type(4))) float f32x4;

__device__ __forceinline__ unsigned short f2bf(float f) {
    union { float f; unsigned u; } v; v.f = f;
    unsigned r = v.u + 0x7fffu + ((v.u >> 16) & 1u);   // round-to-nearest-even
    return (unsigned short)(r >> 16);
}
__device__ __forceinline__ float bflo(unsigned u) {
    union { unsigned u; float f; } v; v.u = u << 16; return v.f;
}
__device__ __forceinline__ float bfhi(unsigned u) {
    union { unsigned u; float f; } v; v.u = u & 0xffff0000u; return v.f;
}

// async global -> LDS, 16B per lane. LDS dest is wave-uniform base; HW writes
// base + lane*16. Global src is per-lane (zero-page / swizzle redirect ok).
__device__ __forceinline__ void gload16(const unsigned short* g, unsigned short* l) {
    __builtin_amdgcn_global_load_lds(
        (const __attribute__((address_space(1))) void*)g,
        (__attribute__((address_space(3))) void*)l, 16, 0, 0);
}

// raw workgroup barrier WITHOUT the vmcnt(0) drain __syncthreads carries;
// sched_barrier(0) pins VMEM/ds/MFMA ordering around it (rule #18).
#define RAW_BARRIER() do { \
    __builtin_amdgcn_sched_barrier(0); \
    __builtin_amdgcn_s_barrier(); \
    __builtin_amdgcn_sched_barrier(0); \
} while (0)

// ---------------------------------------------------------------------------
// Kernel 0: fused prep — main-weight convert (blocks 0..1151), offset-weight
// convert N-padded 18->32 (blocks 1152..1295), zero page (block 1296).
// ---------------------------------------------------------------------------
__global__ __launch_bounds__(256) void prep_kernel(
    const float* __restrict__ cw, const float* __restrict__ ow,
    unsigned short* __restrict__ wt, unsigned short* __restrict__ owt,
    unsigned short* __restrict__ zbuf)
{
    const int bid = blockIdx.x;
    const int tid = threadIdx.x;
    if (bid < 1152) {
        const int i  = bid * 256 + tid;            // 294912 exact
        const int co = i / 1152;
        const int k  = i % 1152;
        const int t  = k >> 7;
        const int ci = k & 127;
        wt[i] = f2bf(cw[((size_t)(co * CIN + ci)) * 9 + t]);
    } else if (bid < 1296) {
        const int i  = (bid - 1152) * 256 + tid;   // 36864 exact
        const int co = i / 1152;
        const int k  = i % 1152;
        const int t  = k >> 7;
        const int ci = k & 127;
        owt[i] = (co < KOFF) ? f2bf(ow[((size_t)(co * CIN + ci)) * 9 + t]) : 0;
    } else {
        zbuf[tid] = 0;
    }
}

// ---------------------------------------------------------------------------
// Kernel 1: x NCHW fp32 -> NHWC bf16 (xh[p][128]) via LDS transpose.
// ---------------------------------------------------------------------------
__global__ __launch_bounds__(256) void nhwc_kernel(
    const float* __restrict__ x, unsigned short* __restrict__ xh)
{
    __shared__ unsigned int sm[64 * 65];
    const int tid = threadIdx.x;
    const int px  = tid & 63;
    const int cig = tid >> 6;
    const int p0  = blockIdx.x * 64;          // 1568 blocks; never straddles b
    const int b   = p0 / HW;
    const int rem0 = p0 % HW;
    const float* xb = x + (size_t)b * CIN * HW + rem0 + px;

    const int c0 = 2 * cig;
#pragma unroll
    for (int k = 0; k < 16; ++k) {
        const int ci = c0 + 8 * k;
        const float a0 = xb[(size_t)ci * HW];
        const float a1 = xb[(size_t)(ci + 1) * HW];
        sm[px * 65 + (ci >> 1)] = (unsigned)f2bf(a0) | ((unsigned)f2bf(a1) << 16);
    }
    __syncthreads();

    const int row = tid >> 2, chunk = tid & 3;
    unsigned int u[16];
#pragma unroll
    for (int c = 0; c < 16; ++c) u[c] = sm[row * 65 + chunk * 16 + c];
    uint4* gv = (uint4*)(xh + ((size_t)(p0 + row)) * 128 + chunk * 32);
#pragma unroll
    for (int j = 0; j < 4; ++j) {
        uint4 t; t.x = u[4*j]; t.y = u[4*j+1]; t.z = u[4*j+2]; t.w = u[4*j+3];
        gv[j] = t;
    }
}

// ---------------------------------------------------------------------------
// Kernel 2: offset conv as implicit-GEMM MFMA (r4-measured, unchanged).
// ---------------------------------------------------------------------------
__global__ __launch_bounds__(256) void offset_mfma_kernel(
    const unsigned short* __restrict__ xh, const unsigned short* __restrict__ owt,
    const float* __restrict__ ob, const unsigned short* __restrict__ zbuf,
    unsigned int* __restrict__ po)
{
    __shared__ __align__(16) unsigned short As[2][128 * BK];  // 32 KB
    __shared__ __align__(16) unsigned short Bs[2][32 * BK];   // 8 KB
    __shared__ float sm_off[128][20];                         // 10.2 KB
    __shared__ float sb_bias[KOFF];

    const int tid  = threadIdx.x;
    const int lane = tid & 63;
    const int wave = tid >> 6;
    const int bid  = blockIdx.x;               // 784 = 8*98 exact
    const int swz  = (bid & 7) * 98 + (bid >> 3);   // bijective XCD swizzle
    const int b    = swz / 98;                 // XCD x -> image x
    const int p0   = (swz % 98) * 128;

    if (tid < KOFF) sb_bias[tid] = ob[tid];

    const int rlane = lane >> 3;         // 0..7 : row within 8-row DMA group
    const int chunk = lane & 7;          // physical 16B chunk this lane writes
    const int csw   = chunk ^ rlane;     // pre-swizzled source chunk

    const unsigned short* xb = xh + (size_t)b * HW * 128;

    int aoff0[4], py4[4], px4[4];
#pragma unroll
    for (int j = 0; j < 4; ++j) {
        const int row = wave * 32 + j * 8 + rlane;
        const int pp  = p0 + row;
        py4[j] = pp / WW; px4[j] = pp % WW;
        aoff0[j] = pp * 128 + csw * 8;
    }
    const int boff = (wave * 8 + rlane) * 1152 + csw * 8;
    const int zoff = (int)(zbuf - xb) + csw * 8;

    const int col  = lane & 15;
    const int quad = lane >> 4;
    const int m0   = wave * 32;
    const int sw   = col & 7;                 // = frag row & 7
    const int cb0  = (quad ^ sw) << 4;        // byte offset of 16B chunk, kk=0
    const int cb1  = ((quad + 4) ^ sw) << 4;  // kk=32

    f32x4 acc[2][2];
#pragma unroll
    for (int i = 0; i < 2; ++i)
#pragma unroll
        for (int j = 0; j < 2; ++j) acc[i][j] = (f32x4)0.f;

    int ao[4];

#define MK_AOFF(T) do { \
    const int dy_ = (T) / 3 - 1, dx_ = (T) % 3 - 1; \
    _Pragma("unroll") for (int j = 0; j < 4; ++j) { \
        const bool v_ = ((unsigned)(py4[j] + dy_) < HH) && ((unsigned)(px4[j] + dx_) < WW); \
        ao[j] = v_ ? (aoff0[j] + (dy_ * WW + dx_) * 128) : zoff; \
    } \
} while (0)

#define STAGE(BUF, T, CI0) do { \
    _Pragma("unroll") for (int j = 0; j < 4; ++j) \
        gload16(xb + ao[j] + (CI0), &As[BUF][(wave * 32 + j * 8) * BK]); \
    gload16(owt + boff + (T) * 128 + (CI0), &Bs[BUF][(wave * 8) * BK]); \
} while (0)

#define COMPUTE(BUF) do { \
    const char* Ab_ = (const char*)As[BUF]; \
    const char* Bb_ = (const char*)Bs[BUF]; \
    short8 af_[2], bf_[2]; \
    _Pragma("unroll") for (int f = 0; f < 2; ++f) \
        af_[f] = *(const short8*)(Ab_ + (m0 + f * 16 + col) * 128 + cb0); \
    _Pragma("unroll") for (int f = 0; f < 2; ++f) \
        bf_[f] = *(const short8*)(Bb_ + (f * 16 + col) * 128 + cb0); \
    _Pragma("unroll") for (int fm = 0; fm < 2; ++fm) \
    _Pragma("unroll") for (int fn = 0; fn < 2; ++fn) \
        acc[fm][fn] = __builtin_amdgcn_mfma_f32_16x16x32_bf16(af_[fm], bf_[fn], acc[fm][fn], 0, 0, 0); \
    _Pragma("unroll") for (int f = 0; f < 2; ++f) \
        af_[f] = *(const short8*)(Ab_ + (m0 + f * 16 + col) * 128 + cb1); \
    _Pragma("unroll") for (int f = 0; f < 2; ++f) \
        bf_[f] = *(const short8*)(Bb_ + (f * 16 + col) * 128 + cb1); \
    _Pragma("unroll") for (int fm = 0; fm < 2; ++fm) \
    _Pragma("unroll") for (int fn = 0; fn < 2; ++fn) \
        acc[fm][fn] = __builtin_amdgcn_mfma_f32_16x16x32_bf16(af_[fm], bf_[fn], acc[fm][fn], 0, 0, 0); \
} while (0)

    MK_AOFF(0);
    STAGE(0, 0, 0);
#pragma unroll
    for (int t = 0; t < 9; ++t) {
        RAW_BARRIER();                               // release buf1
        STAGE(1, t, 64);
        asm volatile("s_waitcnt vmcnt(5)" ::: "memory");   // buf0 loads landed
        RAW_BARRIER();                               // published to all waves
        COMPUTE(0);
        RAW_BARRIER();                               // release buf0
        if (t < 8) {
            MK_AOFF(t + 1);
            STAGE(0, t + 1, 0);
            asm volatile("s_waitcnt vmcnt(5)" ::: "memory");  // buf1 loads landed
        } else {
            asm volatile("s_waitcnt vmcnt(0)" ::: "memory");  // epilogue drain
        }
        RAW_BARRIER();
        COMPUTE(1);
    }
#undef MK_AOFF
#undef STAGE
#undef COMPUTE

    // D (row = m0+fm*16+quad*4+r, col = fn*16+(lane&15)) -> LDS
#pragma unroll
    for (int fm = 0; fm < 2; ++fm)
#pragma unroll
        for (int fn = 0; fn < 2; ++fn) {
            const int c = fn * 16 + col;
            if (c < KOFF) {
                const int rb = m0 + fm * 16 + quad * 4;
#pragma unroll
                for (int r = 0; r < 4; ++r) sm_off[rb + r][c] = acc[fm][fn][r];
            }
        }
    __syncthreads();

    if (tid < 128) {
        unsigned int* pop = po + ((size_t)(b * HW + p0 + tid)) * 9;
#pragma unroll
        for (int s = 0; s < 9; ++s) {
            const float oy = sm_off[tid][s]     + sb_bias[s];
            const float ox = sm_off[tid][9 + s] + sb_bias[9 + s];
            pop[s] = (unsigned)f2bf(oy) | ((unsigned)f2bf(ox) << 16);
        }
    }
}

// ---------------------------------------------------------------------------
// Kernel 3: deformable sampling on NHWC bf16 -> NHWC bf16 (r4-measured,
// unchanged; standalone for occupancy — r7 fusion regressed).
// ---------------------------------------------------------------------------
__global__ __launch_bounds__(256) void sample2_kernel(
    const unsigned short* __restrict__ xh, const unsigned int* __restrict__ po,
    unsigned short* __restrict__ sampled)
{
    const int tid  = threadIdx.x;
    const int lane = tid & 63;
    const int wave = tid >> 6;
    const int ppx  = lane >> 4;
    const int cl   = lane & 15;
    const int bid  = blockIdx.x;               // 6272 = 8*784 exact
    const int swz  = (bid & 7) * 784 + (bid >> 3);  // bijective XCD swizzle
    const int p    = swz * 16 + wave * 4 + ppx;
    const int b    = p / HW;
    const int rem  = p % HW;
    const int y    = rem / WW;
    const int xx   = rem % WW;

    int   idx[9][4];
    float wt[9][4];
    const unsigned int* pop = po + (size_t)p * 9;
#pragma unroll
    for (int s = 0; s < 9; ++s) {
        const int ky = s / 3, kx = s % 3;
        const unsigned u = pop[s];
        const float oy = bflo(u);
        const float ox = bfhi(u);
        const float sy = (float)(y + ky - 1) + oy;
        const float sx = (float)(xx + kx - 1) + ox;
        const float y0f = floorf(sy), x0f = floorf(sx);
        const int   y0 = (int)y0f, x0 = (int)x0f;
        const float wy1 = sy - y0f, wx1 = sx - x0f;
        const float wy0 = 1.f - wy1, wx0 = 1.f - wx1;
        const int y0c = min(max(y0, 0), HH - 1), y1c = min(max(y0 + 1, 0), HH - 1);
        const int x0c = min(max(x0, 0), WW - 1), x1c = min(max(x0 + 1, 0), WW - 1);
        const bool vy0 = (unsigned)y0 < HH, vy1 = (unsigned)(y0 + 1) < HH;
        const bool vx0 = (unsigned)x0 < WW, vx1 = (unsigned)(x0 + 1) < WW;
        idx[s][0] = y0c * WW + x0c; wt[s][0] = (vy0 && vx0) ? wy0 * wx0 : 0.f;
        idx[s][1] = y0c * WW + x1c; wt[s][1] = (vy0 && vx1) ? wy0 * wx1 : 0.f;
        idx[s][2] = y1c * WW + x0c; wt[s][2] = (vy1 && vx0) ? wy1 * wx0 : 0.f;
        idx[s][3] = y1c * WW + x1c; wt[s][3] = (vy1 && vx1) ? wy1 * wx1 : 0.f;
    }

    const unsigned short* xb = xh + ((size_t)b * HW) * 128 + cl * 8;
    float acc[8];
#pragma unroll
    for (int j = 0; j < 8; ++j) acc[j] = 0.f;

#pragma unroll
    for (int s = 0; s < 9; ++s) {
#pragma unroll
        for (int c = 0; c < 4; ++c) {
            const uint4 v = *(const uint4*)(xb + (size_t)idx[s][c] * 128);
            const float w = wt[s][c];
            acc[0] += bflo(v.x) * w; acc[1] += bfhi(v.x) * w;
            acc[2] += bflo(v.y) * w; acc[3] += bfhi(v.y) * w;
            acc[4] += bflo(v.z) * w; acc[5] += bfhi(v.z) * w;
            acc[6] += bflo(v.w) * w; acc[7] += bfhi(v.w) * w;
        }
    }

    uint4 o;
    o.x = (unsigned)f2bf(acc[0]) | ((unsigned)f2bf(acc[1]) << 16);
    o.y = (unsigned)f2bf(acc[2]) | ((unsigned)f2bf(acc[3]) << 16);
    o.z = (unsigned)f2bf(acc[4]) | ((unsigned)f2bf(acc[5]) << 16);
    o.w = (unsigned)f2bf(acc[6]) | ((unsigned)f2bf(acc[7]) << 16);
    *(uint4*)(sampled + (size_t)p * 128 + cl * 8) = o;
}

// ---------------------------------------------------------------------------
// Kernel 4: implicit-GEMM 3x3 conv, BM=224 x BN=256 phase-split schedule.
// Grid 448 = 8 XCD x 56 tiles -> 1.75 blocks/CU -> 87.5% grid util (was
// 76.6% at 392). 8 waves (2M x 4N), per-wave 112x64 out, acc[7][4].
// A-staging: waves 0-6 stage 4 gloads each (224 rows); wave 7 stages B only.
// vmcnt literal stays uniform: pre-wait slot issues 2 B-gloads (all waves),
// so vmcnt(2) drains exactly the own-tile loads (8 for waves 0-6, 4 for
// wave 7). XOR swizzle both-sides; zero-page redirect; image-per-XCD.
// ---------------------------------------------------------------------------
__global__ __launch_bounds__(512, 2) void conv_mfma_kernel(
    const unsigned short* __restrict__ sampled, const unsigned short* __restrict__ wt,
    const unsigned short* __restrict__ zbuf, float* __restrict__ out)
{
    __shared__ __align__(16) unsigned short As[2][BM3 * BK];   // 56 KB
    __shared__ __align__(16) unsigned short Bs[2][256 * BK];   // 64 KB

    const int tid  = threadIdx.x;
    const int lane = tid & 63;
    const int wid  = tid >> 6;                 // 0..7
    const int bid  = blockIdx.x;               // 448 = 8*56 exact
    const int swz  = (bid & 7) * 56 + (bid >> 3);   // bijective XCD swizzle
    const int b    = swz / 56;                 // XCD x -> image x
    const int p0   = (swz % 56) * BM3;

    const int rlane = lane >> 3;         // 0..7 : row within 8-row DMA group
    const int chunk = lane & 7;          // physical 16B chunk this lane writes
    const int csw   = chunk ^ rlane;     // pre-swizzled source chunk

    const unsigned short* sb = sampled + (size_t)b * HW * 128;

    // A-staging rows (waves 0-6 only): rows wid*32 + j*8 + rlane  (0..223)
    // B-staging rows (all 8 waves):    rows wid*32 + j*8 + rlane  (0..255)
    int aoff0[4], boff0[4], py4[4], px4[4];
#pragma unroll
    for (int j = 0; j < 4; ++j) {
        const int row = wid * 32 + j * 8 + rlane;
        const int pp  = min(p0 + row, HW - 1);      // clamp (wave 7 rows unused)
        py4[j] = pp / WW; px4[j] = pp % WW;
        aoff0[j] = pp * 128 + csw * 8;
        boff0[j] = row * 1152 + csw * 8;            // full Cout
    }
    const int zoff = (int)(zbuf - sb) + csw * 8;

    const int col  = lane & 15;
    const int quad = lane >> 4;
    const int wr   = (wid >> 2) * 112;        // M-group: 0 or 112
    const int wc   = (wid & 3) * 64;          // N-group: 0/64/128/192
    const int sw   = col & 7;                 // = frag row & 7
    const int cb0  = (quad ^ sw) << 4;        // byte offset of 16B chunk, kk=0
    const int cb1  = ((quad + 4) ^ sw) << 4;  // kk=32

    f32x4 acc[7][4];
#pragma unroll
    for (int i = 0; i < 7; ++i)
#pragma unroll
        for (int j = 0; j < 4; ++j) acc[i][j] = (f32x4)0.f;

    short8 bf_[8];
    int ao[4], aon[4];

#define MK_AOFF(AO, TAP) do { \
    const int dy_ = (TAP) / 3 - 1, dx_ = (TAP) % 3 - 1; \
    const int d_  = (dy_ * WW + dx_) * 128; \
    _Pragma("unroll") for (int j = 0; j < 4; ++j) { \
        const bool v_ = ((unsigned)(py4[j] + dy_) < HH) && ((unsigned)(px4[j] + dx_) < WW); \
        AO[j] = v_ ? (aoff0[j] + d_) : zoff; \
    } \
} while (0)

#define ISSUE_A2(BUF, AO, J0, CI) do { \
    gload16(sb + AO[J0] + (CI),       &As[BUF][(wid * 32 + (J0) * 8) * BK]); \
    gload16(sb + AO[(J0) + 1] + (CI), &As[BUF][(wid * 32 + ((J0) + 1) * 8) * BK]); \
} while (0)

#define ISSUE_B2(BUF, TAP, J0, CI) do { \
    gload16(wt + boff0[J0] + (TAP) * 128 + (CI),       &Bs[BUF][(wid * 32 + (J0) * 8) * BK]); \
    gload16(wt + boff0[(J0) + 1] + (TAP) * 128 + (CI), &Bs[BUF][(wid * 32 + ((J0) + 1) * 8) * BK]); \
} while (0)

#define PH_B_READ(BUF) do { \
    const char* Bb_ = (const char*)Bs[BUF]; \
    _Pragma("unroll") for (int fn = 0; fn < 4; ++fn) { \
        bf_[fn * 2]     = *(const short8*)(Bb_ + (wc + fn * 16 + col) * 128 + cb0); \
        bf_[fn * 2 + 1] = *(const short8*)(Bb_ + (wc + fn * 16 + col) * 128 + cb1); \
    } \
} while (0)

// two M-frags (2P, 2P+1), 16 MFMA
#define PHASE2F(BUF, P) do { \
    const char* Ab_ = (const char*)As[BUF]; \
    short8 a0k0 = *(const short8*)(Ab_ + (wr + (2 * (P)) * 16 + col) * 128 + cb0); \
    short8 a0k1 = *(const short8*)(Ab_ + (wr + (2 * (P)) * 16 + col) * 128 + cb1); \
    short8 a1k0 = *(const short8*)(Ab_ + (wr + (2 * (P) + 1) * 16 + col) * 128 + cb0); \
    short8 a1k1 = *(const short8*)(Ab_ + (wr + (2 * (P) + 1) * 16 + col) * 128 + cb1); \
    asm volatile("s_waitcnt lgkmcnt(0)" ::: "memory"); \
    __builtin_amdgcn_sched_barrier(0); \
    __builtin_amdgcn_s_setprio(1); \
    _Pragma("unroll") for (int fn = 0; fn < 4; ++fn) { \
        acc[2 * (P)][fn]     = __builtin_amdgcn_mfma_f32_16x16x32_bf16(a0k0, bf_[fn * 2],     acc[2 * (P)][fn],     0, 0, 0); \
        acc[2 * (P)][fn]     = __builtin_amdgcn_mfma_f32_16x16x32_bf16(a0k1, bf_[fn * 2 + 1], acc[2 * (P)][fn],     0, 0, 0); \
        acc[2 * (P) + 1][fn] = __builtin_amdgcn_mfma_f32_16x16x32_bf16(a1k0, bf_[fn * 2],     acc[2 * (P) + 1][fn], 0, 0, 0); \
        acc[2 * (P) + 1][fn] = __builtin_amdgcn_mfma_f32_16x16x32_bf16(a1k1, bf_[fn * 2 + 1], acc[2 * (P) + 1][fn], 0, 0, 0); \
    } \
    __builtin_amdgcn_s_setprio(0); \
} while (0)

// last M-frag (6), 8 MFMA
#define PHASE1F(BUF) do { \
    const char* Ab_ = (const char*)As[BUF]; \
    short8 a0k0 = *(const short8*)(Ab_ + (wr + 96 + col) * 128 + cb0); \
    short8 a0k1 = *(const short8*)(Ab_ + (wr + 96 + col) * 128 + cb1); \
    asm volatile("s_waitcnt lgkmcnt(0)" ::: "memory"); \
    __builtin_amdgcn_sched_barrier(0); \
    __builtin_amdgcn_s_setprio(1); \
    _Pragma("unroll") for (int fn = 0; fn < 4; ++fn) { \
        acc[6][fn] = __builtin_amdgcn_mfma_f32_16x16x32_bf16(a0k0, bf_[fn * 2],     acc[6][fn], 0, 0, 0); \
        acc[6][fn] = __builtin_amdgcn_mfma_f32_16x16x32_bf16(a0k1, bf_[fn * 2 + 1], acc[6][fn], 0, 0, 0); \
    } \
    __builtin_amdgcn_s_setprio(0); \
} while (0)

    // prologue: stage K-tile 0 (tap 0, ci=0) into buf0
    MK_AOFF(ao, 0);
    ISSUE_B2(0, 0, 0, 0); ISSUE_B2(0, 0, 2, 0);
    if (wid < 7) { ISSUE_A2(0, ao, 0, 0); ISSUE_A2(0, ao, 2, 0); }

#pragma unroll 1
    for (int t = 0; t < 9; ++t) {
        // ---- K-tile 2t : read buf0 (ci=0) ; prefetch 2t+1 -> buf1 ----
        RAW_BARRIER();                                   // buf1 free (all waves)
        ISSUE_B2(1, t, 0, 64);                           // uniform pre-wait pair
        asm volatile("s_waitcnt vmcnt(2)" ::: "memory"); // own buf0 loads landed
        RAW_BARRIER();                                   // buf0 published
        PH_B_READ(0);
        PHASE2F(0, 0);
        ISSUE_B2(1, t, 2, 64);
        PHASE2F(0, 1);
        if (wid < 7) ISSUE_A2(1, ao, 0, 64);
        PHASE2F(0, 2);
        if (wid < 7) ISSUE_A2(1, ao, 2, 64);
        PHASE1F(0);
        // ---- K-tile 2t+1 : read buf1 (ci=64) ; prefetch 2t+2 -> buf0 ----
        RAW_BARRIER();                                   // buf0 free
        if (t < 8) {
            ISSUE_B2(0, t + 1, 0, 0);                    // uniform pre-wait pair
            asm volatile("s_waitcnt vmcnt(2)" ::: "memory");
        } else {
            asm volatile("s_waitcnt vmcnt(0)" ::: "memory");  // final drain
        }
        RAW_BARRIER();                                   // buf1 published
        if (t < 8) MK_AOFF(aon, t + 1);
        PH_B_READ(1);
        PHASE2F(1, 0);
        if (t < 8) ISSUE_B2(0, t + 1, 2, 0);
        PHASE2F(1, 1);
        if (t < 8 && wid < 7) ISSUE_A2(0, aon, 0, 0);
        PHASE2F(1, 2);
        if (t < 8 && wid < 7) ISSUE_A2(0, aon, 2, 0);
        PHASE1F(1);
        if (t < 8) {
#pragma unroll
            for (int j = 0; j < 4; ++j) ao[j] = aon[j];
        }
    }
#undef MK_AOFF
#undef ISSUE_A2
#undef ISSUE_B2
#undef PH_B_READ
#undef PHASE2F
#undef PHASE1F

    // C-write: row = p0 + wr + fm*16 + quad*4 + r, col = wc + fn*16 + (lane&15)
#pragma unroll
    for (int fm = 0; fm < 7; ++fm) {
        const int pix = p0 + wr + fm * 16 + quad * 4;
#pragma unroll
        for (int fn = 0; fn < 4; ++fn) {
            const int co = wc + fn * 16 + col;
            float* op = out + ((size_t)(b * COUT + co)) * HW + pix;
            *(f32x4*)op = acc[fm][fn];
        }
    }
}

// ---------------------------------------------------------------------------
extern "C" void kernel_launch(void* const* d_in, const int* in_sizes, int n_in,
                              void* d_out, int out_size, void* d_ws, size_t ws_size,
                              hipStream_t stream)
{
    const float* x  = (const float*)d_in[0];   // (8,128,112,112)
    const float* ow = (const float*)d_in[1];   // (18,128,3,3)
    const float* ob = (const float*)d_in[2];   // (18,)
    const float* cw = (const float*)d_in[3];   // (256,128,3,3)
    float* out = (float*)d_out;                // (8,256,112,112)

    // ws: po 3.6MB | sampled 25.7MB | wt 0.59MB | xh 25.7MB | owt 74KB | zbuf 512B
    unsigned int*   po      = (unsigned int*)d_ws;
    unsigned short* sampled = (unsigned short*)(po + (size_t)NPIX * 9);
    unsigned short* wtb     = sampled + (size_t)NPIX * 128;
    unsigned short* xh      = wtb + (size_t)COUT * 1152;
    unsigned short* owt     = xh + (size_t)NPIX * 128;
    unsigned short* zbuf    = owt + (size_t)32 * 1152;

    prep_kernel<<<dim3(1297), dim3(256), 0, stream>>>(cw, ow, wtb, owt, zbuf);
    nhwc_kernel<<<dim3(NPIX / 64), dim3(256), 0, stream>>>(x, xh);
    offset_mfma_kernel<<<dim3(784), dim3(256), 0, stream>>>(xh, owt, ob, zbuf, po);
    sample2_kernel<<<dim3(NPIX / 16), dim3(256), 0, stream>>>(xh, po, sampled);
    conv_mfma_kernel<<<dim3(448), dim3(512), 0, stream>>>(sampled, wtb, zbuf, out);
}